// Round 7
// baseline (79.563 us; speedup 1.0000x reference)
//
#include <hip/hip_runtime.h>

// PrRoIPool2D(16,16) over full 32x32 box == fixed separable 4-tap resize.
// N=128, C=512. Wave-private, zero in-loop barriers. R6 lesson: staging
// ds_writes drained vmcnt to 0 every plane (write of the last reg waits all
// loads) -> per-wave in-flight bytes collapsed once per plane. Fix: register
// double-buffer vA/vB and issue plane p+1's loads BEFORE plane p's ds_writes,
// so the oldest-reg write needs only vmcnt(7)..(4): >=4KB/wave always in
// flight. Also: vertical-first separable compute (56 VALU/plane vs 128) and
// nontemporal output stores (write stream never re-read).
#define H1 32
#define W1 32
#define NPLANES (128 * 512)
#define NBLK 2048
#define WPB 4                          // waves per block
#define PPW (NPLANES / (NBLK * WPB))   // 8 planes per wave
#define RSTRIDE 36                     // floats per LDS row (144B, b128-aligned)
#define SLAB (H1 * RSTRIDE)            // 1152 floats per wave slab

typedef float f32x4 __attribute__((ext_vector_type(4)));

__device__ __forceinline__ float tri_G(float t) {
    // antiderivative of max(0, 1-|t|), clamped to support
    t = fminf(1.0f, fmaxf(-1.0f, t));
    return (t <= 0.0f) ? 0.5f * (t + 1.0f) * (t + 1.0f)
                       : 0.5f + t - 0.5f * t * t;
}

__global__ __launch_bounds__(256, 4) void prroi_resize_kernel(
    const float* __restrict__ in, float* __restrict__ out) {
    // +4 front pad: col -1 of row 0 / wave 0 stays in-bounds (and zero)
    __shared__ float xs[4 + WPB * SLAB];

    const int t = threadIdx.x;
    const int w = t >> 6;  // wave index -> private slab, private planes
    const int l = t & 63;
    float* const slab = &xs[4 + w * SLAB];

    // one-time zero so pad cols / 0-weight taps read 0.0 (never stale NaN)
#pragma unroll
    for (int q = 0; q < SLAB / 64; ++q) slab[q * 64 + l] = 0.0f;
    if (t < 4) xs[t] = 0.0f;
    __syncthreads();  // once; cross-wave pad visibility (never in the loop)

    // ---- per-lane geometry: 4 outputs (i, 4g..4g+3) of own plane ----
    const int i = l >> 2;
    const int g = l & 3;

    const float binsz = 31.0f / 16.0f;
    const float inv_area = 1.0f / (binsz * binsz);
    const float ey0 = i * binsz, ey1 = ey0 + binsz;
    float wy[4];
#pragma unroll
    for (int k = 0; k < 4; ++k) {  // taps p = 2i-1+k; edge taps -> weight 0
        const float p = (float)(2 * i - 1 + k);
        wy[k] = (tri_G(ey1 - p) - tri_G(ey0 - p)) * inv_area;
    }
    float wx[4][4];
#pragma unroll
    for (int jj = 0; jj < 4; ++jj) {
        const int j = 4 * g + jj;
        const float ex0 = j * binsz, ex1 = ex0 + binsz;
#pragma unroll
        for (int m = 0; m < 4; ++m) {
            const float p = (float)(2 * j - 1 + m);
            wx[jj][m] = tri_G(ex1 - p) - tri_G(ex0 - p);
        }
    }
    // row read bases: row 2i-1+k clamped (clamped rows pair with 0 weights),
    // col base 8g-1 (g==0 hits the zeroed pad at base-1)
    const float* rb[4];
#pragma unroll
    for (int k = 0; k < 4; ++k) {
        const int r = min(max(2 * i - 1 + k, 0), H1 - 1);
        rb[k] = slab + r * RSTRIDE + 8 * g - 1;
    }
    // staging: granule q*64+l -> row q*8+(l>>3), cols (l&7)*4 (16B aligned)
    float* const stb = slab + (l >> 3) * RSTRIDE + ((l & 7) << 2);

    // ---- streams ----
    const int p0 = (blockIdx.x * WPB + w) * PPW;
    const f32x4* src = reinterpret_cast<const f32x4*>(in) + (size_t)p0 * 256 + l;
    f32x4* dst = reinterpret_cast<f32x4*>(out) + (size_t)p0 * 64 + l;

    // two register plane-buffers; fully-unrolled loop keeps indices static
    f32x4 v[2][4];
    v[0][0] = src[0]; v[0][1] = src[64]; v[0][2] = src[128]; v[0][3] = src[192];
    src += 256;

#pragma unroll
    for (int p = 0; p < PPW; ++p) {
        const int cur = p & 1, nxt = cur ^ 1;
        // issue NEXT plane's loads first: staging writes below then only need
        // vmcnt(7)..(4) for the current regs -> never drain to zero in flight
        if (p + 1 < PPW) {
            v[nxt][0] = src[0];  v[nxt][1] = src[64];
            v[nxt][2] = src[128]; v[nxt][3] = src[192];
            src += 256;
        }
        // stage plane p (compiler-counted vmcnt per reg, oldest-first)
        *reinterpret_cast<f32x4*>(stb) = v[cur][0];
        *reinterpret_cast<f32x4*>(stb + 8 * RSTRIDE) = v[cur][1];
        *reinterpret_cast<f32x4*>(stb + 16 * RSTRIDE) = v[cur][2];
        *reinterpret_cast<f32x4*>(stb + 24 * RSTRIDE) = v[cur][3];

        // same-wave DS pipe is in-order: reads see the writes above, and next
        // iteration's writes can't pass these reads. No syncs, single buffer.
        // vertical-first separable pass: tmp[c] = sum_k wy[k]*row_k[c]
        float tmp[10];
#pragma unroll
        for (int c = 0; c < 10; ++c) tmp[c] = 0.0f;
#pragma unroll
        for (int k = 0; k < 4; ++k) {
            const float* r = rb[k];
#pragma unroll
            for (int c = 0; c < 10; ++c) tmp[c] = fmaf(wy[k], r[c], tmp[c]);
        }
        // horizontal: 4 outputs from overlapping 4-tap windows (stride 2)
        f32x4 res;
#pragma unroll
        for (int jj = 0; jj < 4; ++jj) {
            res[jj] = tmp[2 * jj] * wx[jj][0] + tmp[2 * jj + 1] * wx[jj][1] +
                      tmp[2 * jj + 2] * wx[jj][2] + tmp[2 * jj + 3] * wx[jj][3];
        }
        // one coalesced 1KB NT store per wave (don't cache the write stream)
        __builtin_nontemporal_store(res, dst);
        dst += 64;
    }
}

extern "C" void kernel_launch(void* const* d_in, const int* in_sizes, int n_in,
                              void* d_out, int out_size, void* d_ws,
                              size_t ws_size, hipStream_t stream) {
    const float* in = (const float*)d_in[0];
    float* out = (float*)d_out;
    prroi_resize_kernel<<<NBLK, WPB * 64, 0, stream>>>(in, out);
}

// Round 8
// 67.724 us; speedup vs baseline: 1.1748x; 1.1748x over previous
//
#include <hip/hip_runtime.h>

// PrRoIPool2D(16,16) over full 32x32 box == fixed separable 4-tap resize.
// N=128, C=512. Wave-private: each wave owns 8 planes; per plane: 4 dwordx4
// loads -> private LDS slab -> 4 outputs/lane (shared 10-float row reads)
// -> one dwordx4 store. No barriers in the loop (same-wave DS ordering).
// Uniform tap window h0'(i)=2i-1 / w0'(j)=2j-1: edge taps have weight==0
// (pads zeroed once so 0-weight never multiplies garbage/NaN).
// R4 lesson: launch_bounds(256,8) forced VGPR<=64 -> spills. Use (256,4).
// R7 lesson: 3 changes at once regressed (confounded). This round = R6 +
// ONLY the load-reorder: plane p+1's loads issue BEFORE plane p's ds_writes
// (register double-buffer), so staging waits at vmcnt(7..4), never 0 --
// the wave always keeps >=4KB in flight. Store and compute identical to R6.
#define H1 32
#define W1 32
#define NPLANES (128 * 512)
#define NBLK 2048
#define WPB 4                          // waves per block
#define PPW (NPLANES / (NBLK * WPB))   // 8 planes per wave
#define RSTRIDE 36                     // floats per LDS row (144B, b128-aligned)
#define SLAB (H1 * RSTRIDE)            // 1152 floats per wave slab

typedef float f32x4 __attribute__((ext_vector_type(4)));

__device__ __forceinline__ float tri_G(float t) {
    // antiderivative of max(0, 1-|t|), clamped to support
    t = fminf(1.0f, fmaxf(-1.0f, t));
    return (t <= 0.0f) ? 0.5f * (t + 1.0f) * (t + 1.0f)
                       : 0.5f + t - 0.5f * t * t;
}

__global__ __launch_bounds__(256, 4) void prroi_resize_kernel(
    const float* __restrict__ in, float* __restrict__ out) {
    // +4 front pad: col -1 of row 0 / wave 0 stays in-bounds (and zero)
    __shared__ float xs[4 + WPB * SLAB];

    const int t = threadIdx.x;
    const int w = t >> 6;  // wave index -> private slab, private planes
    const int l = t & 63;
    float* const slab = &xs[4 + w * SLAB];

    // one-time zero so pad cols / 0-weight taps read 0.0 (never stale NaN)
#pragma unroll
    for (int q = 0; q < SLAB / 64; ++q) slab[q * 64 + l] = 0.0f;
    if (t < 4) xs[t] = 0.0f;
    __syncthreads();  // once; cross-wave pad visibility (never in the loop)

    // ---- per-lane geometry: 4 outputs (i, 4g..4g+3) of own plane ----
    const int i = l >> 2;
    const int g = l & 3;

    const float binsz = 31.0f / 16.0f;
    const float inv_area = 1.0f / (binsz * binsz);
    const float ey0 = i * binsz, ey1 = ey0 + binsz;
    float wy[4];
#pragma unroll
    for (int k = 0; k < 4; ++k) {  // taps p = 2i-1+k; edge taps -> weight 0
        const float p = (float)(2 * i - 1 + k);
        wy[k] = (tri_G(ey1 - p) - tri_G(ey0 - p)) * inv_area;
    }
    float wx[4][4];
#pragma unroll
    for (int jj = 0; jj < 4; ++jj) {
        const int j = 4 * g + jj;
        const float ex0 = j * binsz, ex1 = ex0 + binsz;
#pragma unroll
        for (int m = 0; m < 4; ++m) {
            const float p = (float)(2 * j - 1 + m);
            wx[jj][m] = tri_G(ex1 - p) - tri_G(ex0 - p);
        }
    }
    // row read bases: row 2i-1+k clamped (clamped rows pair with 0 weights),
    // col base 8g-1 (g==0 hits the zeroed pad at base-1)
    const float* rb[4];
#pragma unroll
    for (int k = 0; k < 4; ++k) {
        const int r = min(max(2 * i - 1 + k, 0), H1 - 1);
        rb[k] = slab + r * RSTRIDE + 8 * g - 1;
    }
    // staging: granule q*64+l -> row q*8+(l>>3), cols (l&7)*4 (16B aligned)
    float* const stb = slab + (l >> 3) * RSTRIDE + ((l & 7) << 2);

    // ---- streams ----
    const int p0 = (blockIdx.x * WPB + w) * PPW;
    const f32x4* src = reinterpret_cast<const f32x4*>(in) + (size_t)p0 * 256 + l;
    f32x4* dst = reinterpret_cast<f32x4*>(out) + (size_t)p0 * 64 + l;

    // two register plane-buffers; unroll-by-2 keeps v-indices static
    f32x4 v[2][4];
    v[0][0] = src[0]; v[0][1] = src[64]; v[0][2] = src[128]; v[0][3] = src[192];
    src += 256;

#pragma unroll 2
    for (int p = 0; p < PPW; ++p) {
        const int cur = p & 1, nxt = cur ^ 1;
        // issue NEXT plane's loads first: the staging writes below then wait
        // only vmcnt(7)..(4) for the current regs -> never drain to zero
        if (p + 1 < PPW) {
            v[nxt][0] = src[0];   v[nxt][1] = src[64];
            v[nxt][2] = src[128]; v[nxt][3] = src[192];
            src += 256;
        }
        // stage plane p (compiler-counted vmcnt per reg, oldest-first)
        *reinterpret_cast<f32x4*>(stb) = v[cur][0];
        *reinterpret_cast<f32x4*>(stb + 8 * RSTRIDE) = v[cur][1];
        *reinterpret_cast<f32x4*>(stb + 16 * RSTRIDE) = v[cur][2];
        *reinterpret_cast<f32x4*>(stb + 24 * RSTRIDE) = v[cur][3];

        // same-wave DS pipe is in-order: no sync needed, single buffer safe
        float a0 = 0.f, a1 = 0.f, a2 = 0.f, a3 = 0.f;
#pragma unroll
        for (int k = 0; k < 4; ++k) {
            const float* r = rb[k];
            const float c0 = r[0], c1 = r[1], c2 = r[2], c3 = r[3], c4 = r[4];
            const float c5 = r[5], c6 = r[6], c7 = r[7], c8 = r[8], c9 = r[9];
            a0 = fmaf(wy[k], c0*wx[0][0] + c1*wx[0][1] + c2*wx[0][2] + c3*wx[0][3], a0);
            a1 = fmaf(wy[k], c2*wx[1][0] + c3*wx[1][1] + c4*wx[1][2] + c5*wx[1][3], a1);
            a2 = fmaf(wy[k], c4*wx[2][0] + c5*wx[2][1] + c6*wx[2][2] + c7*wx[2][3], a2);
            a3 = fmaf(wy[k], c6*wx[3][0] + c7*wx[3][1] + c8*wx[3][2] + c9*wx[3][3], a3);
        }

        f32x4 res = {a0, a1, a2, a3};  // one coalesced 1KB store per wave
        dst[0] = res;
        dst += 64;
    }
}

extern "C" void kernel_launch(void* const* d_in, const int* in_sizes, int n_in,
                              void* d_out, int out_size, void* d_ws,
                              size_t ws_size, hipStream_t stream) {
    const float* in = (const float*)d_in[0];
    float* out = (float*)d_out;
    prroi_resize_kernel<<<NBLK, WPB * 64, 0, stream>>>(in, out);
}

// Round 9
// 63.338 us; speedup vs baseline: 1.2562x; 1.0692x over previous
//
#include <hip/hip_runtime.h>

// PrRoIPool2D(16,16) over full 32x32 box == fixed separable 4-tap resize.
// N=128, C=512. Wave-private: each wave owns 8 planes; per plane: 4 dwordx4
// loads -> private LDS slab -> 4 outputs/lane (shared 10-float row reads)
// -> one dwordx4 store. No barriers in the loop (same-wave DS ordering).
// Uniform tap window h0'(i)=2i-1 / w0'(j)=2j-1: edge taps have weight==0
// (pads zeroed once so 0-weight never multiplies garbage/NaN).
// R4: launch_bounds(256,8) VGPR cap 64 -> spills. Use (256,4).
// R7: confounded 3-change bundle regressed. R8: load-reorder alone neutral
// -> latency-exposure theory dead. This round = R6 + ONE change: nontemporal
// input loads (input stream 268MB > 256MB L3, touched once -> default
// allocate-on-fill churns L3; `nt` marks lines no-allocate/evict-first).
#define H1 32
#define W1 32
#define NPLANES (128 * 512)
#define NBLK 2048
#define WPB 4                          // waves per block
#define PPW (NPLANES / (NBLK * WPB))   // 8 planes per wave
#define RSTRIDE 36                     // floats per LDS row (144B, b128-aligned)
#define SLAB (H1 * RSTRIDE)            // 1152 floats per wave slab

typedef float f32x4 __attribute__((ext_vector_type(4)));

__device__ __forceinline__ float tri_G(float t) {
    // antiderivative of max(0, 1-|t|), clamped to support
    t = fminf(1.0f, fmaxf(-1.0f, t));
    return (t <= 0.0f) ? 0.5f * (t + 1.0f) * (t + 1.0f)
                       : 0.5f + t - 0.5f * t * t;
}

__global__ __launch_bounds__(256, 4) void prroi_resize_kernel(
    const float* __restrict__ in, float* __restrict__ out) {
    // +4 front pad: col -1 of row 0 / wave 0 stays in-bounds (and zero)
    __shared__ float xs[4 + WPB * SLAB];

    const int t = threadIdx.x;
    const int w = t >> 6;  // wave index -> private slab, private planes
    const int l = t & 63;
    float* const slab = &xs[4 + w * SLAB];

    // one-time zero so pad cols / 0-weight taps read 0.0 (never stale NaN)
#pragma unroll
    for (int q = 0; q < SLAB / 64; ++q) slab[q * 64 + l] = 0.0f;
    if (t < 4) xs[t] = 0.0f;
    __syncthreads();  // once; cross-wave pad visibility (never in the loop)

    // ---- per-lane geometry: 4 outputs (i, 4g..4g+3) of own plane ----
    const int i = l >> 2;
    const int g = l & 3;

    const float binsz = 31.0f / 16.0f;
    const float inv_area = 1.0f / (binsz * binsz);
    const float ey0 = i * binsz, ey1 = ey0 + binsz;
    float wy[4];
#pragma unroll
    for (int k = 0; k < 4; ++k) {  // taps p = 2i-1+k; edge taps -> weight 0
        const float p = (float)(2 * i - 1 + k);
        wy[k] = (tri_G(ey1 - p) - tri_G(ey0 - p)) * inv_area;
    }
    float wx[4][4];
#pragma unroll
    for (int jj = 0; jj < 4; ++jj) {
        const int j = 4 * g + jj;
        const float ex0 = j * binsz, ex1 = ex0 + binsz;
#pragma unroll
        for (int m = 0; m < 4; ++m) {
            const float p = (float)(2 * j - 1 + m);
            wx[jj][m] = tri_G(ex1 - p) - tri_G(ex0 - p);
        }
    }
    // row read bases: row 2i-1+k clamped (clamped rows pair with 0 weights),
    // col base 8g-1 (g==0 hits the zeroed pad at base-1)
    const float* rb[4];
#pragma unroll
    for (int k = 0; k < 4; ++k) {
        const int r = min(max(2 * i - 1 + k, 0), H1 - 1);
        rb[k] = slab + r * RSTRIDE + 8 * g - 1;
    }
    // staging: granule q*64+l -> row q*8+(l>>3), cols (l&7)*4 (16B aligned)
    float* const stb = slab + (l >> 3) * RSTRIDE + ((l & 7) << 2);

    // ---- streams ----
    const int p0 = (blockIdx.x * WPB + w) * PPW;
    const f32x4* src = reinterpret_cast<const f32x4*>(in) + (size_t)p0 * 256 + l;
    f32x4* dst = reinterpret_cast<f32x4*>(out) + (size_t)p0 * 64 + l;

    // depth-1 prefetch prologue (nontemporal: stream-once, don't cache)
    f32x4 v0 = __builtin_nontemporal_load(src);
    f32x4 v1 = __builtin_nontemporal_load(src + 64);
    f32x4 v2 = __builtin_nontemporal_load(src + 128);
    f32x4 v3 = __builtin_nontemporal_load(src + 192);
    src += 256;

#pragma unroll 2
    for (int p = 0; p < PPW; ++p) {
        // stage plane p (compiler-counted vmcnt waits per v)
        *reinterpret_cast<f32x4*>(stb) = v0;
        *reinterpret_cast<f32x4*>(stb + 8 * RSTRIDE) = v1;
        *reinterpret_cast<f32x4*>(stb + 16 * RSTRIDE) = v2;
        *reinterpret_cast<f32x4*>(stb + 24 * RSTRIDE) = v3;
        if (p + 1 < PPW) {  // issue next plane; lands during compute
            v0 = __builtin_nontemporal_load(src);
            v1 = __builtin_nontemporal_load(src + 64);
            v2 = __builtin_nontemporal_load(src + 128);
            v3 = __builtin_nontemporal_load(src + 192);
            src += 256;
        }

        // same-wave DS pipe is in-order: no sync needed, single buffer safe
        float a0 = 0.f, a1 = 0.f, a2 = 0.f, a3 = 0.f;
#pragma unroll
        for (int k = 0; k < 4; ++k) {
            const float* r = rb[k];
            const float c0 = r[0], c1 = r[1], c2 = r[2], c3 = r[3], c4 = r[4];
            const float c5 = r[5], c6 = r[6], c7 = r[7], c8 = r[8], c9 = r[9];
            a0 = fmaf(wy[k], c0*wx[0][0] + c1*wx[0][1] + c2*wx[0][2] + c3*wx[0][3], a0);
            a1 = fmaf(wy[k], c2*wx[1][0] + c3*wx[1][1] + c4*wx[1][2] + c5*wx[1][3], a1);
            a2 = fmaf(wy[k], c4*wx[2][0] + c5*wx[2][1] + c6*wx[2][2] + c7*wx[2][3], a2);
            a3 = fmaf(wy[k], c6*wx[3][0] + c7*wx[3][1] + c8*wx[3][2] + c9*wx[3][3], a3);
        }

        f32x4 res = {a0, a1, a2, a3};  // one coalesced 1KB store per wave
        dst[0] = res;
        dst += 64;
    }
}

extern "C" void kernel_launch(void* const* d_in, const int* in_sizes, int n_in,
                              void* d_out, int out_size, void* d_ws,
                              size_t ws_size, hipStream_t stream) {
    const float* in = (const float*)d_in[0];
    float* out = (float*)d_out;
    prroi_resize_kernel<<<NBLK, WPB * 64, 0, stream>>>(in, out);
}

// Round 10
// 61.332 us; speedup vs baseline: 1.2973x; 1.0327x over previous
//
#include <hip/hip_runtime.h>

// PrRoIPool2D(16,16) over full 32x32 box == fixed separable 4-tap resize.
// N=128, C=512. Wave-private: each wave owns 8 planes; per plane: 4 dwordx4
// loads -> private LDS slab -> 4 outputs/lane (shared 10-float row reads)
// -> one dwordx4 store. No barriers in the loop (same-wave DS ordering).
// Uniform tap window h0'(i)=2i-1 / w0'(j)=2j-1: edge taps have weight==0
// (pads zeroed once so 0-weight never multiplies garbage/NaN).
// R4: launch_bounds(256,8) VGPR cap 64 -> spills. Use (256,4).
// R8: load-reorder neutral -> latency-exposure theory dead.
// R9: NT input loads 66.0->63.3us (L3 churn on 268MB touched-once stream
// confirmed). This round = R9 + ONE change: NT output stores (67MB write
// stream never re-read; avoid write-allocate competing for cache fill).
#define H1 32
#define W1 32
#define NPLANES (128 * 512)
#define NBLK 2048
#define WPB 4                          // waves per block
#define PPW (NPLANES / (NBLK * WPB))   // 8 planes per wave
#define RSTRIDE 36                     // floats per LDS row (144B, b128-aligned)
#define SLAB (H1 * RSTRIDE)            // 1152 floats per wave slab

typedef float f32x4 __attribute__((ext_vector_type(4)));

__device__ __forceinline__ float tri_G(float t) {
    // antiderivative of max(0, 1-|t|), clamped to support
    t = fminf(1.0f, fmaxf(-1.0f, t));
    return (t <= 0.0f) ? 0.5f * (t + 1.0f) * (t + 1.0f)
                       : 0.5f + t - 0.5f * t * t;
}

__global__ __launch_bounds__(256, 4) void prroi_resize_kernel(
    const float* __restrict__ in, float* __restrict__ out) {
    // +4 front pad: col -1 of row 0 / wave 0 stays in-bounds (and zero)
    __shared__ float xs[4 + WPB * SLAB];

    const int t = threadIdx.x;
    const int w = t >> 6;  // wave index -> private slab, private planes
    const int l = t & 63;
    float* const slab = &xs[4 + w * SLAB];

    // one-time zero so pad cols / 0-weight taps read 0.0 (never stale NaN)
#pragma unroll
    for (int q = 0; q < SLAB / 64; ++q) slab[q * 64 + l] = 0.0f;
    if (t < 4) xs[t] = 0.0f;
    __syncthreads();  // once; cross-wave pad visibility (never in the loop)

    // ---- per-lane geometry: 4 outputs (i, 4g..4g+3) of own plane ----
    const int i = l >> 2;
    const int g = l & 3;

    const float binsz = 31.0f / 16.0f;
    const float inv_area = 1.0f / (binsz * binsz);
    const float ey0 = i * binsz, ey1 = ey0 + binsz;
    float wy[4];
#pragma unroll
    for (int k = 0; k < 4; ++k) {  // taps p = 2i-1+k; edge taps -> weight 0
        const float p = (float)(2 * i - 1 + k);
        wy[k] = (tri_G(ey1 - p) - tri_G(ey0 - p)) * inv_area;
    }
    float wx[4][4];
#pragma unroll
    for (int jj = 0; jj < 4; ++jj) {
        const int j = 4 * g + jj;
        const float ex0 = j * binsz, ex1 = ex0 + binsz;
#pragma unroll
        for (int m = 0; m < 4; ++m) {
            const float p = (float)(2 * j - 1 + m);
            wx[jj][m] = tri_G(ex1 - p) - tri_G(ex0 - p);
        }
    }
    // row read bases: row 2i-1+k clamped (clamped rows pair with 0 weights),
    // col base 8g-1 (g==0 hits the zeroed pad at base-1)
    const float* rb[4];
#pragma unroll
    for (int k = 0; k < 4; ++k) {
        const int r = min(max(2 * i - 1 + k, 0), H1 - 1);
        rb[k] = slab + r * RSTRIDE + 8 * g - 1;
    }
    // staging: granule q*64+l -> row q*8+(l>>3), cols (l&7)*4 (16B aligned)
    float* const stb = slab + (l >> 3) * RSTRIDE + ((l & 7) << 2);

    // ---- streams ----
    const int p0 = (blockIdx.x * WPB + w) * PPW;
    const f32x4* src = reinterpret_cast<const f32x4*>(in) + (size_t)p0 * 256 + l;
    f32x4* dst = reinterpret_cast<f32x4*>(out) + (size_t)p0 * 64 + l;

    // depth-1 prefetch prologue (nontemporal: stream-once, don't cache)
    f32x4 v0 = __builtin_nontemporal_load(src);
    f32x4 v1 = __builtin_nontemporal_load(src + 64);
    f32x4 v2 = __builtin_nontemporal_load(src + 128);
    f32x4 v3 = __builtin_nontemporal_load(src + 192);
    src += 256;

#pragma unroll 2
    for (int p = 0; p < PPW; ++p) {
        // stage plane p (compiler-counted vmcnt waits per v)
        *reinterpret_cast<f32x4*>(stb) = v0;
        *reinterpret_cast<f32x4*>(stb + 8 * RSTRIDE) = v1;
        *reinterpret_cast<f32x4*>(stb + 16 * RSTRIDE) = v2;
        *reinterpret_cast<f32x4*>(stb + 24 * RSTRIDE) = v3;
        if (p + 1 < PPW) {  // issue next plane; lands during compute
            v0 = __builtin_nontemporal_load(src);
            v1 = __builtin_nontemporal_load(src + 64);
            v2 = __builtin_nontemporal_load(src + 128);
            v3 = __builtin_nontemporal_load(src + 192);
            src += 256;
        }

        // same-wave DS pipe is in-order: no sync needed, single buffer safe
        float a0 = 0.f, a1 = 0.f, a2 = 0.f, a3 = 0.f;
#pragma unroll
        for (int k = 0; k < 4; ++k) {
            const float* r = rb[k];
            const float c0 = r[0], c1 = r[1], c2 = r[2], c3 = r[3], c4 = r[4];
            const float c5 = r[5], c6 = r[6], c7 = r[7], c8 = r[8], c9 = r[9];
            a0 = fmaf(wy[k], c0*wx[0][0] + c1*wx[0][1] + c2*wx[0][2] + c3*wx[0][3], a0);
            a1 = fmaf(wy[k], c2*wx[1][0] + c3*wx[1][1] + c4*wx[1][2] + c5*wx[1][3], a1);
            a2 = fmaf(wy[k], c4*wx[2][0] + c5*wx[2][1] + c6*wx[2][2] + c7*wx[2][3], a2);
            a3 = fmaf(wy[k], c6*wx[3][0] + c7*wx[3][1] + c8*wx[3][2] + c9*wx[3][3], a3);
        }

        // one coalesced 1KB NT store per wave (write stream never re-read)
        f32x4 res = {a0, a1, a2, a3};
        __builtin_nontemporal_store(res, dst);
        dst += 64;
    }
}

extern "C" void kernel_launch(void* const* d_in, const int* in_sizes, int n_in,
                              void* d_out, int out_size, void* d_ws,
                              size_t ws_size, hipStream_t stream) {
    const float* in = (const float*)d_in[0];
    float* out = (float*)d_out;
    prroi_resize_kernel<<<NBLK, WPB * 64, 0, stream>>>(in, out);
}

// Round 12
// 59.886 us; speedup vs baseline: 1.3286x; 1.0241x over previous
//
#include <hip/hip_runtime.h>

// PrRoIPool2D(16,16) over full 32x32 box == fixed separable 4-tap resize.
// N=128, C=512. Wave-private: each wave owns 8 planes; per plane: 4 NT
// dwordx4 loads -> private LDS slab -> 4 outputs/lane (shared 10-float row
// reads) -> one NT dwordx4 store. No barriers AT ALL (same-wave DS ordering;
// slab[-1] is written only by this wave's l==32 lane -- no cross-wave alias).
// Ladder: R4 spills (launch_bounds(256,8)); R8 load-reorder neutral (not
// latency-bound, 8x MLP oversubscribed); R9 NT loads -2.7us; R10 NT stores
// -2.0us (L3 churn confirmed); R7's regression == vertical-first VALU (by
// elimination) - avoided. This round: prologue streamlining only - first
// plane's loads issue BEFORE weight math, and zero only the pad cells
// actually read (col 32/row + slab[-1]) instead of the whole slab+sync.
// (R11 was an infrastructure failure - same kernel resubmitted.)
#define H1 32
#define W1 32
#define NPLANES (128 * 512)
#define NBLK 2048
#define WPB 4                          // waves per block
#define PPW (NPLANES / (NBLK * WPB))   // 8 planes per wave
#define RSTRIDE 36                     // floats per LDS row (144B, b128-aligned)
#define SLAB (H1 * RSTRIDE)            // 1152 floats per wave slab

typedef float f32x4 __attribute__((ext_vector_type(4)));

__device__ __forceinline__ float tri_G(float t) {
    // antiderivative of max(0, 1-|t|), clamped to support
    t = fminf(1.0f, fmaxf(-1.0f, t));
    return (t <= 0.0f) ? 0.5f * (t + 1.0f) * (t + 1.0f)
                       : 0.5f + t - 0.5f * t * t;
}

__global__ __launch_bounds__(256, 4) void prroi_resize_kernel(
    const float* __restrict__ in, float* __restrict__ out) {
    // +4 front pad: slab[-1] of wave 0 stays in-bounds (and zero)
    __shared__ float xs[4 + WPB * SLAB];

    const int t = threadIdx.x;
    const int w = t >> 6;  // wave index -> private slab, private planes
    const int l = t & 63;
    float* const slab = &xs[4 + w * SLAB];

    // ---- FIRST: get the plane-0 requests into the memory system ----
    const int p0 = (blockIdx.x * WPB + w) * PPW;
    const f32x4* src = reinterpret_cast<const f32x4*>(in) + (size_t)p0 * 256 + l;
    f32x4 v0 = __builtin_nontemporal_load(src);
    f32x4 v1 = __builtin_nontemporal_load(src + 64);
    f32x4 v2 = __builtin_nontemporal_load(src + 128);
    f32x4 v3 = __builtin_nontemporal_load(src + 192);
    src += 256;

    // ---- minimal pad zero (only cells ever read with 0-weight taps):
    // col 32 of each row, and slab[-1] (only this wave's l==32 lane writes
    // it; wave w-1 never touches its own col-35 tail, so no alias).
    // Same-wave DS order makes these visible to this wave's later reads.
    if (l < 32) slab[l * RSTRIDE + 32] = 0.0f;
    else if (l == 32) slab[-1] = 0.0f;

    // ---- per-lane geometry: 4 outputs (i, 4g..4g+3) of own plane ----
    const int i = l >> 2;
    const int g = l & 3;

    const float binsz = 31.0f / 16.0f;
    const float inv_area = 1.0f / (binsz * binsz);
    const float ey0 = i * binsz, ey1 = ey0 + binsz;
    float wy[4];
#pragma unroll
    for (int k = 0; k < 4; ++k) {  // taps p = 2i-1+k; edge taps -> weight 0
        const float p = (float)(2 * i - 1 + k);
        wy[k] = (tri_G(ey1 - p) - tri_G(ey0 - p)) * inv_area;
    }
    float wx[4][4];
#pragma unroll
    for (int jj = 0; jj < 4; ++jj) {
        const int j = 4 * g + jj;
        const float ex0 = j * binsz, ex1 = ex0 + binsz;
#pragma unroll
        for (int m = 0; m < 4; ++m) {
            const float p = (float)(2 * j - 1 + m);
            wx[jj][m] = tri_G(ex1 - p) - tri_G(ex0 - p);
        }
    }
    // row read bases: row 2i-1+k clamped (clamped rows pair with 0 weights),
    // col base 8g-1 (g==0 reads slab[-1] / prior row's zeroed pad)
    const float* rb[4];
#pragma unroll
    for (int k = 0; k < 4; ++k) {
        const int r = min(max(2 * i - 1 + k, 0), H1 - 1);
        rb[k] = slab + r * RSTRIDE + 8 * g - 1;
    }
    // staging: granule q*64+l -> row q*8+(l>>3), cols (l&7)*4 (16B aligned)
    float* const stb = slab + (l >> 3) * RSTRIDE + ((l & 7) << 2);

    f32x4* dst = reinterpret_cast<f32x4*>(out) + (size_t)p0 * 64 + l;

#pragma unroll 2
    for (int p = 0; p < PPW; ++p) {
        // stage plane p (compiler-counted vmcnt waits per v)
        *reinterpret_cast<f32x4*>(stb) = v0;
        *reinterpret_cast<f32x4*>(stb + 8 * RSTRIDE) = v1;
        *reinterpret_cast<f32x4*>(stb + 16 * RSTRIDE) = v2;
        *reinterpret_cast<f32x4*>(stb + 24 * RSTRIDE) = v3;
        if (p + 1 < PPW) {  // issue next plane; lands during compute
            v0 = __builtin_nontemporal_load(src);
            v1 = __builtin_nontemporal_load(src + 64);
            v2 = __builtin_nontemporal_load(src + 128);
            v3 = __builtin_nontemporal_load(src + 192);
            src += 256;
        }

        // same-wave DS pipe is in-order: no sync needed, single buffer safe
        float a0 = 0.f, a1 = 0.f, a2 = 0.f, a3 = 0.f;
#pragma unroll
        for (int k = 0; k < 4; ++k) {
            const float* r = rb[k];
            const float c0 = r[0], c1 = r[1], c2 = r[2], c3 = r[3], c4 = r[4];
            const float c5 = r[5], c6 = r[6], c7 = r[7], c8 = r[8], c9 = r[9];
            a0 = fmaf(wy[k], c0*wx[0][0] + c1*wx[0][1] + c2*wx[0][2] + c3*wx[0][3], a0);
            a1 = fmaf(wy[k], c2*wx[1][0] + c3*wx[1][1] + c4*wx[1][2] + c5*wx[1][3], a1);
            a2 = fmaf(wy[k], c4*wx[2][0] + c5*wx[2][1] + c6*wx[2][2] + c7*wx[2][3], a2);
            a3 = fmaf(wy[k], c6*wx[3][0] + c7*wx[3][1] + c8*wx[3][2] + c9*wx[3][3], a3);
        }

        // one coalesced 1KB NT store per wave (write stream never re-read)
        f32x4 res = {a0, a1, a2, a3};
        __builtin_nontemporal_store(res, dst);
        dst += 64;
    }
}

extern "C" void kernel_launch(void* const* d_in, const int* in_sizes, int n_in,
                              void* d_out, int out_size, void* d_ws,
                              size_t ws_size, hipStream_t stream) {
    const float* in = (const float*)d_in[0];
    float* out = (float*)d_out;
    prroi_resize_kernel<<<NBLK, WPB * 64, 0, stream>>>(in, out);
}